// Round 7
// baseline (449.196 us; speedup 1.0000x reference)
//
#include <hip/hip_runtime.h>

#define N_AUTHORS 50000
#define N_PAPERS  100000
#define N_NODES   150000
#define N_EDGES   1200000
#define EMB       64

#define NBUCK     586          // ceil(150000/256), bucket = row >> 8
#define NSUB      (NBUCK * 8)  // 4688 (bucket, blockgroup) sub-regions
#define NBLK_A    512
#define CHUNK_A   ((N_EDGES + NBLK_A - 1) / NBLK_A)   // 2344

// bf16 helpers (plain ushort storage)
__device__ __forceinline__ float bf2f(ushort u) {
    return __uint_as_float(((unsigned)u) << 16);
}
__device__ __forceinline__ ushort f2bf(float f) {   // round-to-nearest-even
    unsigned u = __float_as_uint(f);
    return (ushort)((u + 0x7fffu + ((u >> 16) & 1u)) >> 16);
}

// ---------------- init: ego = concat(author, paper); acc = ego; x0 = bf16(ego)
__global__ void lgcn_init(const float* __restrict__ a,
                          const float* __restrict__ p,
                          float* __restrict__ ego_out,
                          float* __restrict__ acc,
                          ushort* __restrict__ x0) {
    size_t i = (size_t)blockIdx.x * blockDim.x + threadIdx.x;  // float4 index
    const size_t n4  = (size_t)N_NODES  * EMB / 4;
    const size_t au4 = (size_t)N_AUTHORS * EMB / 4;
    if (i >= n4) return;
    float4 v = (i < au4) ? ((const float4*)a)[i] : ((const float4*)p)[i - au4];
    ((float4*)ego_out)[i] = v;
    ((float4*)acc)[i]     = v;
    ushort4 b;
    b.x = f2bf(v.x); b.y = f2bf(v.y); b.z = f2bf(v.z); b.w = f2bf(v.w);
    ((ushort4*)x0)[i] = b;
}

// ---------------- row histogram + row_start scan ----------------------------
__global__ void lgcn_hist(const int* __restrict__ rows, unsigned* __restrict__ counts) {
    int e = blockIdx.x * blockDim.x + threadIdx.x;
    if (e >= N_EDGES) return;
    atomicAdd(&counts[rows[e]], 1u);
}

__global__ void lgcn_scan_blocks(const unsigned* __restrict__ counts,
                                 unsigned* __restrict__ row_start,
                                 unsigned* __restrict__ bsum) {
    __shared__ unsigned s[256];
    int t = threadIdx.x;
    int i = blockIdx.x * 256 + t;
    unsigned v = (i < N_NODES) ? counts[i] : 0u;
    s[t] = v;
    __syncthreads();
    for (int d = 1; d < 256; d <<= 1) {
        unsigned u = (t >= d) ? s[t - d] : 0u;
        __syncthreads();
        s[t] += u;
        __syncthreads();
    }
    if (i < N_NODES + 1) row_start[i] = s[t] - v;   // exclusive
    if (t == 255) bsum[blockIdx.x] = s[255];        // block total
}

__global__ void lgcn_scan_top(const unsigned* __restrict__ bsum,
                              unsigned* __restrict__ bsum_ex, int nb) {
    __shared__ unsigned s[1024];
    int t = threadIdx.x;
    unsigned v = (t < nb) ? bsum[t] : 0u;
    s[t] = v;
    __syncthreads();
    for (int d = 1; d < 1024; d <<= 1) {
        unsigned u = (t >= d) ? s[t - d] : 0u;
        __syncthreads();
        s[t] += u;
        __syncthreads();
    }
    bsum_ex[t] = s[t] - v;                          // exclusive
}

__global__ void lgcn_scan_add(unsigned* __restrict__ row_start,
                              const unsigned* __restrict__ bsum_ex) {
    int i = blockIdx.x * 256 + threadIdx.x;
    if (i >= N_NODES + 1) return;
    row_start[i] += bsum_ex[i >> 8];
}

// ---------------- two-phase bucketed edge binning ---------------------------
// phase 0: sub-region histogram (same edge->block mapping as lgcn_bin)
__global__ void lgcn_sub_hist(const int* __restrict__ rows,
                              unsigned* __restrict__ sub_count) {
    int blk = blockIdx.x;
    int g   = blk & 7;
    int base = blk * CHUNK_A;
    int end  = base + CHUNK_A; if (end > N_EDGES) end = N_EDGES;
    for (int e = base + threadIdx.x; e < end; e += blockDim.x) {
        int b = rows[e] >> 8;
        atomicAdd(&sub_count[b * 8 + g], 1u);
    }
}

// exclusive scan over NSUB=4688 values -> sub_cursor (single block, 1024 thr)
__global__ void lgcn_sub_scan(const unsigned* __restrict__ sub_count,
                              unsigned* __restrict__ sub_cursor) {
    __shared__ unsigned s[1024];
    const int PER = (NSUB + 1023) / 1024;   // 5
    int t = threadIdx.x;
    unsigned local[PER];
    unsigned sum = 0;
    for (int k = 0; k < PER; ++k) {
        int i = t * PER + k;
        unsigned v = (i < NSUB) ? sub_count[i] : 0u;
        local[k] = sum;                      // exclusive within chunk
        sum += v;
    }
    s[t] = sum;
    __syncthreads();
    for (int d = 1; d < 1024; d <<= 1) {
        unsigned u = (t >= d) ? s[t - d] : 0u;
        __syncthreads();
        s[t] += u;
        __syncthreads();
    }
    unsigned ex = s[t] - sum;                // exclusive block prefix
    for (int k = 0; k < PER; ++k) {
        int i = t * PER + k;
        if (i < NSUB) sub_cursor[i] = ex + local[k];
    }
}

// pass A: bin edges into (bucket, blockgroup) staging sub-regions
__global__ void lgcn_bin(const int* __restrict__ rows,
                         const int* __restrict__ cols,
                         const float* __restrict__ vals,
                         unsigned* __restrict__ sub_cursor,
                         float2* __restrict__ se_stage,
                         unsigned char* __restrict__ rowloc) {
    int blk = blockIdx.x;
    int g   = blk & 7;
    int base = blk * CHUNK_A;
    int end  = base + CHUNK_A; if (end > N_EDGES) end = N_EDGES;
    for (int e = base + threadIdx.x; e < end; e += blockDim.x) {
        int r = rows[e];
        int b = r >> 8;
        unsigned pos = atomicAdd(&sub_cursor[b * 8 + g], 1u);
        se_stage[pos] = make_float2(__int_as_float(cols[e]), vals[e]);
        rowloc[pos]   = (unsigned char)(r & 255);
    }
}

// pass B: one block per bucket, place staged edges into row-sorted se
__global__ void lgcn_place(const unsigned* __restrict__ row_start,
                           const float2* __restrict__ se_stage,
                           const unsigned char* __restrict__ rowloc,
                           float2* __restrict__ se) {
    __shared__ unsigned cur[256];
    int b  = blockIdx.x;
    int rb = b << 8;
    int nrows = N_NODES - rb; if (nrows > 256) nrows = 256;
    int t = threadIdx.x;
    if (t < nrows) cur[t] = row_start[rb + t];
    __syncthreads();
    unsigned span0 = row_start[rb];
    unsigned span1 = row_start[rb + nrows];
    for (unsigned p = span0 + t; p < span1; p += blockDim.x) {
        float2 v   = se_stage[p];
        unsigned lr = rowloc[p];
        unsigned pos = atomicAdd(&cur[lr], 1u);
        se[pos] = v;
    }
}

// ---------------- fused SpMM + accumulate: one wave per 2 rows --------------
// x, y are bf16; acc is f32 (the output). Interleaved rows -> 4 indep gathers.
template <int FINAL>
__global__ void lgcn_spmm_csr(const unsigned* __restrict__ rs,
                              const float2* __restrict__ se,
                              const ushort* __restrict__ x,
                              ushort* __restrict__ y,     // unused when FINAL
                              float* __restrict__ acc) {
    int w    = blockIdx.x * (blockDim.x >> 6) + (threadIdx.x >> 6);
    int lane = threadIdx.x & 63;
    int r0   = w << 1;
    if (r0 >= N_NODES) return;
    unsigned j0 = rs[r0];
    unsigned m  = rs[r0 + 1];
    unsigned j1 = m;
    unsigned e1 = rs[r0 + 2];
    float a0 = 0.f, a1 = 0.f;
    while (j0 + 2 <= m && j1 + 2 <= e1) {     // 4 independent gathers in flight
        float2 p0 = se[j0], p1 = se[j0 + 1];
        float2 q0 = se[j1], q1 = se[j1 + 1];
        float g0 = bf2f(x[(size_t)__float_as_int(p0.x) * EMB + lane]);
        float g1 = bf2f(x[(size_t)__float_as_int(p1.x) * EMB + lane]);
        float h0 = bf2f(x[(size_t)__float_as_int(q0.x) * EMB + lane]);
        float h1 = bf2f(x[(size_t)__float_as_int(q1.x) * EMB + lane]);
        a0 += p0.y * g0; a0 += p1.y * g1;
        a1 += q0.y * h0; a1 += q1.y * h1;
        j0 += 2; j1 += 2;
    }
    while (j0 + 2 <= m) {
        float2 p0 = se[j0], p1 = se[j0 + 1];
        a0 += p0.y * bf2f(x[(size_t)__float_as_int(p0.x) * EMB + lane]);
        a0 += p1.y * bf2f(x[(size_t)__float_as_int(p1.x) * EMB + lane]);
        j0 += 2;
    }
    if (j0 < m) {
        float2 p0 = se[j0];
        a0 += p0.y * bf2f(x[(size_t)__float_as_int(p0.x) * EMB + lane]);
    }
    while (j1 + 2 <= e1) {
        float2 q0 = se[j1], q1 = se[j1 + 1];
        a1 += q0.y * bf2f(x[(size_t)__float_as_int(q0.x) * EMB + lane]);
        a1 += q1.y * bf2f(x[(size_t)__float_as_int(q1.x) * EMB + lane]);
        j1 += 2;
    }
    if (j1 < e1) {
        float2 q0 = se[j1];
        a1 += q0.y * bf2f(x[(size_t)__float_as_int(q0.x) * EMB + lane]);
    }
    size_t o0 = (size_t)r0 * EMB + lane;
    size_t o1 = o0 + EMB;
    if (FINAL) {
        acc[o0] = (acc[o0] + a0) * 0.25f;
        acc[o1] = (acc[o1] + a1) * 0.25f;
    } else {
        y[o0] = f2bf(a0);
        y[o1] = f2bf(a1);
        acc[o0] += a0;
        acc[o1] += a1;
    }
}

extern "C" void kernel_launch(void* const* d_in, const int* in_sizes, int n_in,
                              void* d_out, int out_size, void* d_ws, size_t ws_size,
                              hipStream_t stream) {
    const float* author = (const float*)d_in[0];
    const float* paper  = (const float*)d_in[1];
    const int*   rows   = (const int*)d_in[2];
    const int*   cols   = (const int*)d_in[3];
    const float* vals   = (const float*)d_in[4];

    float* ego_out = (float*)d_out;                           // 150000*64
    float* acc     = (float*)d_out + (size_t)N_NODES * EMB;   // author||paper

    // workspace layout
    char* w = (char*)d_ws;
    float2*   se        = (float2*)w;   w += (size_t)N_EDGES * sizeof(float2);       // 9.6 MB
    float2*   se_stage  = (float2*)w;   w += (size_t)N_EDGES * sizeof(float2);       // 9.6 MB
    ushort*   xb0       = (ushort*)w;   w += (size_t)N_NODES * EMB * sizeof(ushort); // 19.2 MB
    ushort*   xb1       = (ushort*)w;   w += (size_t)N_NODES * EMB * sizeof(ushort); // 19.2 MB
    unsigned char* rowloc = (unsigned char*)w; w += (size_t)N_EDGES;                 // 1.2 MB
    unsigned* counts    = (unsigned*)w; w += (size_t)N_NODES * 4;                    // 0.6 MB
    unsigned* row_start = (unsigned*)w; w += (size_t)(N_NODES + 1) * 4;              // 0.6 MB
    unsigned* bsum      = (unsigned*)w; w += 1024 * 4;
    unsigned* bsum_ex   = (unsigned*)w; w += 1024 * 4;
    unsigned* sub_count = (unsigned*)w; w += (size_t)NSUB * 4;                       // 18.75 KB
    unsigned* sub_cursor= (unsigned*)w; w += (size_t)NSUB * 4;                       // 18.75 KB

    const int BLK = 256;
    const int NB_SCAN = (N_NODES + 1 + 255) / 256;    // 587
    const int g_edges = (N_EDGES + BLK - 1) / BLK;    // 4688
    const int g_init  = (int)(((size_t)N_NODES * EMB / 4 + BLK - 1) / BLK);
    const int g_spmm  = ((N_NODES / 2) + 3) / 4;      // 2 rows/wave, 4 waves/block

    // init output: ego, acc=ego, x0=bf16(ego)
    lgcn_init<<<g_init, BLK, 0, stream>>>(author, paper, ego_out, acc, xb0);

    // row_start (CSR offsets)
    hipMemsetAsync(counts, 0, (size_t)N_NODES * 4, stream);
    lgcn_hist<<<g_edges, BLK, 0, stream>>>(rows, counts);
    lgcn_scan_blocks<<<NB_SCAN, 256, 0, stream>>>(counts, row_start, bsum);
    lgcn_scan_top<<<1, 1024, 0, stream>>>(bsum, bsum_ex, NB_SCAN);
    lgcn_scan_add<<<NB_SCAN, 256, 0, stream>>>(row_start, bsum_ex);

    // two-phase bucketed scatter into row-sorted se
    hipMemsetAsync(sub_count, 0, (size_t)NSUB * 4, stream);
    lgcn_sub_hist<<<NBLK_A, BLK, 0, stream>>>(rows, sub_count);
    lgcn_sub_scan<<<1, 1024, 0, stream>>>(sub_count, sub_cursor);
    lgcn_bin<<<NBLK_A, BLK, 0, stream>>>(rows, cols, vals, sub_cursor, se_stage, rowloc);
    lgcn_place<<<NBUCK, BLK, 0, stream>>>(row_start, se_stage, rowloc, se);

    // 3 fused propagation layers (bf16 x/y, f32 acc)
    lgcn_spmm_csr<0><<<g_spmm, BLK, 0, stream>>>(row_start, se, xb0, xb1, acc);
    lgcn_spmm_csr<0><<<g_spmm, BLK, 0, stream>>>(row_start, se, xb1, xb0, acc);
    lgcn_spmm_csr<1><<<g_spmm, BLK, 0, stream>>>(row_start, se, xb0, xb1, acc);
}

// Round 8
// 322.821 us; speedup vs baseline: 1.3915x; 1.3915x over previous
//
#include <hip/hip_runtime.h>

#define N_AUTHORS 50000
#define N_PAPERS  100000
#define N_NODES   150000
#define N_EDGES   1200000
#define EMB       64

// bf16 helpers (plain ushort storage)
__device__ __forceinline__ float bf2f(ushort u) {
    return __uint_as_float(((unsigned)u) << 16);
}
__device__ __forceinline__ ushort f2bf(float f) {   // round-to-nearest-even
    unsigned u = __float_as_uint(f);
    return (ushort)((u + 0x7fffu + ((u >> 16) & 1u)) >> 16);
}

// ---------------- init: ego(f32,out) + ego(bf16 scratch) --------------------
__global__ void lgcn_init(const float* __restrict__ a,
                          const float* __restrict__ p,
                          float* __restrict__ ego_out,
                          ushort* __restrict__ x0) {
    size_t i = (size_t)blockIdx.x * blockDim.x + threadIdx.x;  // float4 index
    const size_t n4  = (size_t)N_NODES  * EMB / 4;
    const size_t au4 = (size_t)N_AUTHORS * EMB / 4;
    if (i >= n4) return;
    float4 v = (i < au4) ? ((const float4*)a)[i] : ((const float4*)p)[i - au4];
    ((float4*)ego_out)[i] = v;
    ushort4 b;
    b.x = f2bf(v.x); b.y = f2bf(v.y); b.z = f2bf(v.z); b.w = f2bf(v.w);
    ((ushort4*)x0)[i] = b;
}

// ---------------- CSR build ------------------------------------------------
__global__ void lgcn_hist(const int* __restrict__ rows, unsigned* __restrict__ counts) {
    int e = blockIdx.x * blockDim.x + threadIdx.x;
    if (e >= N_EDGES) return;
    atomicAdd(&counts[rows[e]], 1u);
}

__global__ void lgcn_scan_blocks(const unsigned* __restrict__ counts,
                                 unsigned* __restrict__ row_start,
                                 unsigned* __restrict__ bsum) {
    __shared__ unsigned s[256];
    int t = threadIdx.x;
    int i = blockIdx.x * 256 + t;
    unsigned v = (i < N_NODES) ? counts[i] : 0u;
    s[t] = v;
    __syncthreads();
    for (int d = 1; d < 256; d <<= 1) {
        unsigned u = (t >= d) ? s[t - d] : 0u;
        __syncthreads();
        s[t] += u;
        __syncthreads();
    }
    if (i < N_NODES + 1) row_start[i] = s[t] - v;   // exclusive
    if (t == 255) bsum[blockIdx.x] = s[255];        // block total
}

__global__ void lgcn_scan_top(const unsigned* __restrict__ bsum,
                              unsigned* __restrict__ bsum_ex, int nb) {
    __shared__ unsigned s[1024];
    int t = threadIdx.x;
    unsigned v = (t < nb) ? bsum[t] : 0u;
    s[t] = v;
    __syncthreads();
    for (int d = 1; d < 1024; d <<= 1) {
        unsigned u = (t >= d) ? s[t - d] : 0u;
        __syncthreads();
        s[t] += u;
        __syncthreads();
    }
    bsum_ex[t] = s[t] - v;                          // exclusive
}

__global__ void lgcn_scan_add(unsigned* __restrict__ row_start,
                              const unsigned* __restrict__ bsum_ex,
                              unsigned* __restrict__ cursor) {
    int i = blockIdx.x * 256 + threadIdx.x;
    if (i >= N_NODES + 1) return;
    unsigned rv = row_start[i] + bsum_ex[i >> 8];
    row_start[i] = rv;
    if (i < N_NODES) cursor[i] = rv;
}

__global__ void lgcn_scatter(const int* __restrict__ rows,
                             const int* __restrict__ cols,
                             const float* __restrict__ vals,
                             unsigned* __restrict__ cursor,
                             float2* __restrict__ se) {
    int e = blockIdx.x * blockDim.x + threadIdx.x;
    if (e >= N_EDGES) return;
    int r = rows[e];
    unsigned pos = atomicAdd(&cursor[r], 1u);
    se[pos] = make_float2(__int_as_float(cols[e]), vals[e]);
}

// ---------------- SpMM: one wave per row, 4 edges per load instruction ------
// Lane l: edge slot g=l>>4, dims d4=(l&15)*4 .. +3.  Each lane loads ushort4
// (8B); a 16-lane group covers one edge's full 128B row.  Cross-lane reduce
// (xor 16, 32) sums the 4 edge slots.  x,y bf16.
__global__ void lgcn_spmm(const unsigned* __restrict__ rs,
                          const float2* __restrict__ se,
                          const ushort* __restrict__ x,
                          ushort* __restrict__ y) {
    int w    = blockIdx.x * (blockDim.x >> 6) + (threadIdx.x >> 6);
    int lane = threadIdx.x & 63;
    if (w >= N_NODES) return;
    unsigned j   = rs[w];
    unsigned end = rs[w + 1];
    const int g  = lane >> 4;
    const int d4 = (lane & 15) << 2;
    float a0 = 0.f, a1 = 0.f, a2 = 0.f, a3 = 0.f;

    while (j + 4 < end) {                 // full group at j, masked at j+4
        float2 eA = se[j + g];
        unsigned iB = j + 4 + g;
        float2 eB;
        if (iB < end) eB = se[iB];
        else { eB.x = __int_as_float(0); eB.y = 0.f; }
        ushort4 xA = *(const ushort4*)(x + ((size_t)__float_as_int(eA.x) << 6) + d4);
        ushort4 xB = *(const ushort4*)(x + ((size_t)__float_as_int(eB.x) << 6) + d4);
        a0 += eA.y * bf2f(xA.x); a1 += eA.y * bf2f(xA.y);
        a2 += eA.y * bf2f(xA.z); a3 += eA.y * bf2f(xA.w);
        a0 += eB.y * bf2f(xB.x); a1 += eB.y * bf2f(xB.y);
        a2 += eB.y * bf2f(xB.z); a3 += eB.y * bf2f(xB.w);
        j += 8;
    }
    if (j < end) {                        // final masked group (1..4 edges)
        unsigned i = j + g;
        float2 e;
        if (i < end) e = se[i];
        else { e.x = __int_as_float(0); e.y = 0.f; }
        ushort4 xv = *(const ushort4*)(x + ((size_t)__float_as_int(e.x) << 6) + d4);
        a0 += e.y * bf2f(xv.x); a1 += e.y * bf2f(xv.y);
        a2 += e.y * bf2f(xv.z); a3 += e.y * bf2f(xv.w);
    }

    // reduce across the 4 edge slots (lanes l, l^16, l^32, l^48)
    a0 += __shfl_xor(a0, 16, 64); a0 += __shfl_xor(a0, 32, 64);
    a1 += __shfl_xor(a1, 16, 64); a1 += __shfl_xor(a1, 32, 64);
    a2 += __shfl_xor(a2, 16, 64); a2 += __shfl_xor(a2, 32, 64);
    a3 += __shfl_xor(a3, 16, 64); a3 += __shfl_xor(a3, 32, 64);

    if (g == 0) {
        ushort4 o;
        o.x = f2bf(a0); o.y = f2bf(a1); o.z = f2bf(a2); o.w = f2bf(a3);
        *(ushort4*)(y + ((size_t)w << 6) + d4) = o;
    }
}

// ---------------- merge: out = 0.25*(ego + y1 + y2 + y3) --------------------
__global__ void lgcn_merge(const float* __restrict__ ego,
                           const ushort* __restrict__ y1,
                           const ushort* __restrict__ y2,
                           const ushort* __restrict__ y3,
                           float* __restrict__ out) {
    size_t i = (size_t)blockIdx.x * blockDim.x + threadIdx.x;  // x4 index
    const size_t n4 = (size_t)N_NODES * EMB / 4;
    if (i >= n4) return;
    float4  e  = ((const float4*)ego)[i];
    ushort4 b1 = ((const ushort4*)y1)[i];
    ushort4 b2 = ((const ushort4*)y2)[i];
    ushort4 b3 = ((const ushort4*)y3)[i];
    float4 r;
    r.x = 0.25f * (e.x + bf2f(b1.x) + bf2f(b2.x) + bf2f(b3.x));
    r.y = 0.25f * (e.y + bf2f(b1.y) + bf2f(b2.y) + bf2f(b3.y));
    r.z = 0.25f * (e.z + bf2f(b1.z) + bf2f(b2.z) + bf2f(b3.z));
    r.w = 0.25f * (e.w + bf2f(b1.w) + bf2f(b2.w) + bf2f(b3.w));
    ((float4*)out)[i] = r;
}

extern "C" void kernel_launch(void* const* d_in, const int* in_sizes, int n_in,
                              void* d_out, int out_size, void* d_ws, size_t ws_size,
                              hipStream_t stream) {
    const float* author = (const float*)d_in[0];
    const float* paper  = (const float*)d_in[1];
    const int*   rows   = (const int*)d_in[2];
    const int*   cols   = (const int*)d_in[3];
    const float* vals   = (const float*)d_in[4];

    float* ego_out = (float*)d_out;                           // 150000*64 f32
    float* acc     = (float*)d_out + (size_t)N_NODES * EMB;   // author||paper f32

    // workspace layout (~67.5 MB)
    char* w = (char*)d_ws;
    float2*   se        = (float2*)w;   w += (size_t)N_EDGES * sizeof(float2);       // 9.6 MB
    ushort*   xbE       = (ushort*)w;   w += (size_t)N_NODES * EMB * sizeof(ushort); // 19.2 MB (ego bf16, reused as y3)
    ushort*   xb1       = (ushort*)w;   w += (size_t)N_NODES * EMB * sizeof(ushort); // 19.2 MB (y1)
    ushort*   xb2       = (ushort*)w;   w += (size_t)N_NODES * EMB * sizeof(ushort); // 19.2 MB (y2)
    unsigned* counts    = (unsigned*)w; w += (size_t)N_NODES * 4;                    // 0.6 MB (cursor alias)
    unsigned* row_start = (unsigned*)w; w += (size_t)(N_NODES + 1) * 4;              // 0.6 MB
    unsigned* bsum      = (unsigned*)w; w += 1024 * 4;
    unsigned* bsum_ex   = (unsigned*)w; w += 1024 * 4;
    unsigned* cursor    = counts;       // counts dead after scan_blocks

    const int BLK = 256;
    const int NB_SCAN = (N_NODES + 1 + 255) / 256;    // 587
    const int g_edges = (N_EDGES + BLK - 1) / BLK;    // 4688
    const int g_vec   = (int)(((size_t)N_NODES * EMB / 4 + BLK - 1) / BLK);
    const int g_spmm  = (N_NODES + 3) / 4;            // 1 row/wave, 4 waves/block

    // init: ego (f32, out) + ego (bf16 scratch)
    lgcn_init<<<g_vec, BLK, 0, stream>>>(author, paper, ego_out, xbE);

    // CSR offsets
    hipMemsetAsync(counts, 0, (size_t)N_NODES * 4, stream);
    lgcn_hist<<<g_edges, BLK, 0, stream>>>(rows, counts);
    lgcn_scan_blocks<<<NB_SCAN, 256, 0, stream>>>(counts, row_start, bsum);
    lgcn_scan_top<<<1, 1024, 0, stream>>>(bsum, bsum_ex, NB_SCAN);
    lgcn_scan_add<<<NB_SCAN, 256, 0, stream>>>(row_start, bsum_ex, cursor);

    // row-sorted edge array
    lgcn_scatter<<<g_edges, BLK, 0, stream>>>(rows, cols, vals, cursor, se);

    // 3 propagation layers (bf16), no acc RMW
    lgcn_spmm<<<g_spmm, BLK, 0, stream>>>(row_start, se, xbE, xb1);
    lgcn_spmm<<<g_spmm, BLK, 0, stream>>>(row_start, se, xb1, xb2);
    lgcn_spmm<<<g_spmm, BLK, 0, stream>>>(row_start, se, xb2, xbE);  // y3 -> xbE

    // out = 0.25*(ego + y1 + y2 + y3)
    lgcn_merge<<<g_vec, BLK, 0, stream>>>(ego_out, xb1, xb2, xbE, acc);
}